// Round 10
// baseline (71.671 us; speedup 1.0000x reference)
//
#include <hip/hip_runtime.h>
#include <hip/hip_cooperative_groups.h>

namespace cg = cooperative_groups;

// ================= Fused cooperative kernel =================
// grid = 256 (1 block/CU), block = 1024 (16 waves/CU).
// Block blk owns batch b = blk>>4, tiles tile0=(blk&15)*2 and tile0+1.
// Thread: h = t>>9 (which tile), u = t&511 (within-tile tid).
// x tiles staged ONCE in LDS (64 KB) and reused by every phase.
__global__ __launch_bounds__(1024, 4) void fused(
    const float* __restrict__ x,
    const float* __restrict__ w1,  const float* __restrict__ b1,
    const float* __restrict__ w21, const float* __restrict__ b21,
    const float* __restrict__ w22, const float* __restrict__ b22,
    const float* __restrict__ w3,  const float* __restrict__ b3,
    const float* __restrict__ gamma, const float* __restrict__ beta,
    float* __restrict__ kvpart, float* __restrict__ Wt,
    float* __restrict__ biasv,  float* __restrict__ statsacc,
    float* __restrict__ out)
{
  __shared__ float xt[2*64*128];   // two x tiles, 64 KB, persistent
  __shared__ float buf[8512];      // phase-overlaid scratch, 34 KB
  cg::grid_group grid = cg::this_grid();
  int t = threadIdx.x, blk = blockIdx.x;
  int b = blk >> 4;
  int h = t >> 9, u = t & 511;
  int tile = (blk & 15)*2 + h;
  int pairP = 2*blk + h;                       // global (b,tile) pair index in [0,512)

  if (blk == 0 && t < 128) statsacc[t] = 0.f;  // re-zero every call; used 2 grid.syncs later

  // ---------------- Phase 1: stage x; conv1/conv22 + maxpool; kv partial ----------------
  const float* xb = x + ((size_t)b << 18) + tile*128;
  float* xth = &xt[h*8192];                    // [64][128]
  for (int v = u; v < 2048; v += 512) {
    int ch = v >> 5, rem = v & 31;
    *(float4*)&xth[ch*128 + rem*4] = *(const float4*)(xb + ch*4096 + rem*4);
  }
  {
    float* wlt  = buf;                         // [ch][64]: o<32 w1, o>=32 w22 (4096)
    float* bl   = buf + 4096;                  // 64
    float* phil = buf + 4160 + h*2112;         // [32][33]
    float* glt  = phil + 1056;                 // [32][33]
    {
      int half = t >> 9, vv = t & 511;
      int o = vv >> 4, cb = (vv & 15)*4;
      const float* src = (half ? w22 : w1) + o*64 + cb;
      float4 uu = *(const float4*)src;
      int oo = o + half*32;
      wlt[(cb+0)*64+oo]=uu.x; wlt[(cb+1)*64+oo]=uu.y;
      wlt[(cb+2)*64+oo]=uu.z; wlt[(cb+3)*64+oo]=uu.w;
    }
    if (t < 32) bl[t] = b1[t];
    else if (t < 64) bl[t] = b22[t-32];
    __syncthreads();

    int p = u & 31, og = u >> 5;               // pooled col, output group of 2
    float a0[2][4], a1[2][4];
    #pragma unroll
    for (int k = 0; k < 2; k++)
      #pragma unroll
      for (int px = 0; px < 4; px++) { a0[k][px] = 0.f; a1[k][px] = 0.f; }
    #pragma unroll 4
    for (int c = 0; c < 64; c++) {
      float2 x0 = *(const float2*)&xth[c*128 + 2*p];
      float2 x1 = *(const float2*)&xth[c*128 + 64 + 2*p];
      float2 wa = *(const float2*)&wlt[c*64 + og*2];
      float2 wb = *(const float2*)&wlt[c*64 + 32 + og*2];
      float xs[4]  = {x0.x, x0.y, x1.x, x1.y};
      float was[2] = {wa.x, wa.y};
      float wbs[2] = {wb.x, wb.y};
      #pragma unroll
      for (int k = 0; k < 2; k++)
        #pragma unroll
        for (int px = 0; px < 4; px++) {
          a0[k][px] += was[k] * xs[px];
          a1[k][px] += wbs[k] * xs[px];
        }
    }
    #pragma unroll
    for (int k = 0; k < 2; k++) {
      int o = og*2 + k;
      float m1 = fmaxf(fmaxf(a0[k][0], a0[k][1]), fmaxf(a0[k][2], a0[k][3])) + bl[o];
      float m2 = fmaxf(fmaxf(a1[k][0], a1[k][1]), fmaxf(a1[k][2], a1[k][3])) + bl[32+o];
      glt[p*33 + o]  = m1;    // g[j=o, p]
      phil[o*33 + p] = m2;    // phi[i=o, p]
    }
    __syncthreads();
    float* kvp = kvpart + (size_t)pairP * 1024;
    for (int e = u; e < 1024; e += 512) {
      int i = e >> 5, j = e & 31;
      float s = 0.f;
      #pragma unroll
      for (int q = 0; q < 32; q++) s += phil[i*33 + q] * glt[q*33 + j];
      kvp[e] = s;
    }
  }
  grid.sync();

  // ---------------- Phase 2 (blocks 0..15): reduce kv; W[b]=(w3@kv^T)@w21; bias ----------
  if (blk < 16) {
    float* kvl  = buf;            // 1024: kv[i*32+j] (already /N)
    float* w3t  = buf + 1024;     // [j][64]
    float* w21l = buf + 3072;     // [i][64]
    float* b21l = buf + 5120;     // 32
    int bb = blk;
    {
      const float* kp = kvpart + ((size_t)bb << 15) + t;
      float s = 0.f;
      #pragma unroll
      for (int r = 0; r < 32; r++) s += kp[r*1024];     // coalesced
      kvl[t] = s * (1.f/1024.f);
    }
    for (int e = t; e < 2048; e += 1024) { int c = e >> 5, j = e & 31; w3t[j*64+c] = w3[e]; }
    for (int e = t; e < 2048; e += 1024) { int i = e >> 6, ch = e & 63; w21l[i*64+ch] = w21[e]; }
    if (t < 32) b21l[t] = b21[t];
    __syncthreads();
    if (t < 64) {
      int c = t;
      float A[32];
      #pragma unroll
      for (int i = 0; i < 32; i++) {
        float s = 0.f;
        #pragma unroll
        for (int j = 0; j < 32; j++) s += w3t[j*64+c] * kvl[i*32+j];
        A[i] = s;
      }
      float bias = b3[c];
      #pragma unroll
      for (int i = 0; i < 32; i++) bias += A[i] * b21l[i];
      biasv[bb*64 + c] = bias;
      float* Wb = Wt + (size_t)bb*4096;
      #pragma unroll
      for (int ch = 0; ch < 64; ch++) {
        float s = 0.f;
        #pragma unroll
        for (int i = 0; i < 32; i++) s += A[i] * w21l[i*64+ch];
        Wb[ch*64 + c] = s;                     // Wt[k=ch][c]
      }
    }
  }
  grid.sync();

  // ---------------- Phase 3: z = W[b]@x + bias (acc in regs); BN partial stats -----------
  float* wl    = buf;                          // [k][c] 4096
  float* lstat = buf + 4096;                   // 128
  {
    int v = t;
    *(float4*)&wl[(v>>4)*64 + (v&15)*4] = *(const float4*)(Wt + ((size_t)b << 12) + v*4);
  }
  if (t < 128) lstat[t] = 0.f;
  __syncthreads();

  int pg = u & 15, cg2 = u >> 4;               // 16 px-groups x 32 c-groups
  int p0 = pg*4, c0 = cg2*2;
  float acc[2][8];
  #pragma unroll
  for (int ci = 0; ci < 2; ci++)
    #pragma unroll
    for (int pj = 0; pj < 8; pj++) acc[ci][pj] = 0.f;
  #pragma unroll 4
  for (int k = 0; k < 64; k++) {
    float2 w2 = *(const float2*)&wl[k*64 + c0];
    float4 xa = *(const float4*)&xth[k*128 + p0];
    float4 xc = *(const float4*)&xth[k*128 + p0 + 64];
    float xs[8] = {xa.x, xa.y, xa.z, xa.w, xc.x, xc.y, xc.z, xc.w};
    #pragma unroll
    for (int pj = 0; pj < 8; pj++) {
      acc[0][pj] += w2.x * xs[pj];
      acc[1][pj] += w2.y * xs[pj];
    }
  }
  {
    float2 bb2 = *(const float2*)(biasv + b*64 + c0);
    float bbv[2] = {bb2.x, bb2.y};
    #pragma unroll
    for (int ci = 0; ci < 2; ci++)
      #pragma unroll
      for (int pj = 0; pj < 8; pj++) acc[ci][pj] += bbv[ci];   // acc IS z now
    #pragma unroll
    for (int ci = 0; ci < 2; ci++) {
      float s1 = 0.f, s2 = 0.f;
      #pragma unroll
      for (int pj = 0; pj < 8; pj++) { float z = acc[ci][pj]; s1 += z; s2 += z*z; }
      #pragma unroll
      for (int off = 1; off < 16; off <<= 1) { s1 += __shfl_xor(s1, off); s2 += __shfl_xor(s2, off); }
      if (pg == 0) { atomicAdd(&lstat[c0+ci], s1); atomicAdd(&lstat[64+c0+ci], s2); }
    }
  }
  __syncthreads();
  if (t < 128) atomicAdd(&statsacc[t], lstat[t]);   // 256 blocks x 128
  grid.sync();

  // ---------------- Phase 4: scale/shift; apply to resident acc; + resident x; store -----
  float* scl = buf + 4224;                      // 64
  float* shl = buf + 4288;                      // 64
  if (t < 64) {
    const float inv_cnt = 1.f / 65536.f;        // B*H*W
    float mu  = statsacc[t] * inv_cnt;
    float var = statsacc[64+t] * inv_cnt - mu*mu;
    float sc  = gamma[t] * rsqrtf(var + 1e-5f);
    scl[t] = sc;
    shl[t] = beta[t] - sc*mu;
  }
  __syncthreads();
  float* ob = out + ((size_t)b << 18) + (size_t)tile*128;
  #pragma unroll
  for (int ci = 0; ci < 2; ci++) {
    int c = c0 + ci;
    float sc = scl[c], sh = shl[c];
    float4 xa = *(const float4*)&xth[c*128 + p0];
    float4 xc = *(const float4*)&xth[c*128 + p0 + 64];
    float4 ra, rb;
    ra.x = sc*acc[ci][0] + sh + xa.x;
    ra.y = sc*acc[ci][1] + sh + xa.y;
    ra.z = sc*acc[ci][2] + sh + xa.z;
    ra.w = sc*acc[ci][3] + sh + xa.w;
    rb.x = sc*acc[ci][4] + sh + xc.x;
    rb.y = sc*acc[ci][5] + sh + xc.y;
    rb.z = sc*acc[ci][6] + sh + xc.z;
    rb.w = sc*acc[ci][7] + sh + xc.w;
    *(float4*)(ob + (size_t)c*4096 + p0)      = ra;
    *(float4*)(ob + (size_t)c*4096 + p0 + 64) = rb;
  }
}

// ======================= Fallback path: R9's proven 4 kernels =======================
__global__ __launch_bounds__(256) void k1_kv(const float* __restrict__ x,
    const float* __restrict__ w1, const float* __restrict__ b1,
    const float* __restrict__ w22, const float* __restrict__ b22,
    float* __restrict__ kvpart, float* __restrict__ statsacc)
{
  __shared__ float xl[64][128];
  __shared__ float wlt[64][64];
  __shared__ float bl[64];
  __shared__ float phil[32][33];
  __shared__ float glt[32][33];
  int t = threadIdx.x;
  int b = blockIdx.x >> 5, r = blockIdx.x & 31;
  const float* xb = x + ((size_t)b << 18);
  if (blockIdx.x == 0 && t < 128) statsacc[t] = 0.f;
  for (int v = t; v < 2048; v += 256) {
    int c = v >> 5, rem = v & 31;
    int h2 = rem >> 4, wv = rem & 15;
    float4 u = *(const float4*)(xb + c*4096 + (2*r + h2)*64 + wv*4);
    float* dst = &xl[c][h2*64 + wv*4];
    dst[0] = u.x; dst[1] = u.y; dst[2] = u.z; dst[3] = u.w;
  }
  for (int v = t; v < 1024; v += 256) {
    int half = v >> 9, vv = v & 511;
    int o = vv >> 4, cb = (vv & 15) * 4;
    const float* src = (half ? w22 : w1) + o*64 + cb;
    float4 u = *(const float4*)src;
    int oo = o + half*32;
    wlt[cb+0][oo] = u.x; wlt[cb+1][oo] = u.y; wlt[cb+2][oo] = u.z; wlt[cb+3][oo] = u.w;
  }
  if (t < 32) bl[t] = b1[t];
  else if (t < 64) bl[t] = b22[t-32];
  __syncthreads();
  int p = t & 31, og = t >> 5;
  float acc0[4][4], acc1[4][4];
  #pragma unroll
  for (int k = 0; k < 4; k++)
    #pragma unroll
    for (int px = 0; px < 4; px++) { acc0[k][px] = 0.f; acc1[k][px] = 0.f; }
  #pragma unroll 4
  for (int c = 0; c < 64; c++) {
    float2 x0 = *(const float2*)&xl[c][2*p];
    float2 x1 = *(const float2*)&xl[c][64 + 2*p];
    float4 wa = *(const float4*)&wlt[c][og*4];
    float4 wb = *(const float4*)&wlt[c][32 + og*4];
    float xs[4]  = {x0.x, x0.y, x1.x, x1.y};
    float was[4] = {wa.x, wa.y, wa.z, wa.w};
    float wbs[4] = {wb.x, wb.y, wb.z, wb.w};
    #pragma unroll
    for (int k = 0; k < 4; k++)
      #pragma unroll
      for (int px = 0; px < 4; px++) {
        acc0[k][px] += was[k] * xs[px];
        acc1[k][px] += wbs[k] * xs[px];
      }
  }
  #pragma unroll
  for (int k = 0; k < 4; k++) {
    int o = og*4 + k;
    float m1 = fmaxf(fmaxf(acc0[k][0], acc0[k][1]), fmaxf(acc0[k][2], acc0[k][3])) + bl[o];
    float m2 = fmaxf(fmaxf(acc1[k][0], acc1[k][1]), fmaxf(acc1[k][2], acc1[k][3])) + bl[32+o];
    glt[p][o]  = m1;
    phil[o][p] = m2;
  }
  __syncthreads();
  float* kvp = kvpart + (size_t)blockIdx.x * 1024;
  for (int e = t; e < 1024; e += 256) {
    int i = e >> 5, j = e & 31;
    float s = 0.f;
    #pragma unroll
    for (int q = 0; q < 32; q++) s += phil[i][q] * glt[q][j];
    kvp[e] = s;
  }
}

__global__ __launch_bounds__(256) void k2_wmat(const float* __restrict__ kvpart,
    const float* __restrict__ w3, const float* __restrict__ b3,
    const float* __restrict__ w21, const float* __restrict__ b21,
    float* __restrict__ Wt, float* __restrict__ biasv)
{
  __shared__ float kvl[32][32];
  __shared__ float w3t[32][64];
  __shared__ float w21l[32][64];
  __shared__ float b21l[32];
  int t = threadIdx.x, b = blockIdx.x;
  for (int e = t; e < 1024; e += 256) {
    float s = 0.f;
    const float* kp = kvpart + ((size_t)b << 15) + e;
    #pragma unroll
    for (int r = 0; r < 32; r++) s += kp[r*1024];
    kvl[e>>5][e&31] = s * (1.f/1024.f);
  }
  for (int e = t; e < 2048; e += 256) { int c = e >> 5, j = e & 31; w3t[j][c] = w3[e]; }
  for (int e = t; e < 2048; e += 256) { int i = e >> 6, ch = e & 63; w21l[i][ch] = w21[e]; }
  if (t < 32) b21l[t] = b21[t];
  __syncthreads();
  if (t < 64) {
    int c = t;
    float A[32];
    #pragma unroll
    for (int i = 0; i < 32; i++) {
      float s = 0.f;
      #pragma unroll
      for (int j = 0; j < 32; j++) s += w3t[j][c] * kvl[i][j];
      A[i] = s;
    }
    float bias = b3[c];
    #pragma unroll
    for (int i = 0; i < 32; i++) bias += A[i] * b21l[i];
    biasv[b*64 + c] = bias;
    float* Wb = Wt + (size_t)b*4096;
    #pragma unroll
    for (int ch = 0; ch < 64; ch++) {
      float s = 0.f;
      #pragma unroll
      for (int i = 0; i < 32; i++) s += A[i] * w21l[i][ch];
      Wb[ch*64 + c] = s;
    }
  }
}

__global__ __launch_bounds__(256) void k3_stats(const float* __restrict__ x,
    const float* __restrict__ Wt, const float* __restrict__ biasv,
    float* __restrict__ statsacc)
{
  __shared__ float xt[64][128];
  __shared__ float wl[64][64];
  __shared__ float lstat[128];
  int t = threadIdx.x, blk = blockIdx.x;
  int tile = blk & 31, b = blk >> 5;
  const float* xb = x + ((size_t)b << 18) + tile*128;
  for (int v = t; v < 2048; v += 256) {
    int ch = v >> 5, rem = v & 31;
    *(float4*)&xt[ch][rem*4] = *(const float4*)(xb + ch*4096 + rem*4);
  }
  const float* wb = Wt + ((size_t)b << 12);
  for (int v = t; v < 1024; v += 256)
    *(float4*)&wl[v >> 4][(v & 15)*4] = *(const float4*)(wb + v*4);
  if (t < 128) lstat[t] = 0.f;
  __syncthreads();
  int pg = t & 15, cg = t >> 4;
  int p0 = pg*4, c0 = cg*4;
  float acc[4][8];
  #pragma unroll
  for (int ci = 0; ci < 4; ci++)
    #pragma unroll
    for (int pj = 0; pj < 8; pj++) acc[ci][pj] = 0.f;
  #pragma unroll 4
  for (int k = 0; k < 64; k++) {
    float4 w4 = *(const float4*)&wl[k][c0];
    float4 xa = *(const float4*)&xt[k][p0];
    float4 xc = *(const float4*)&xt[k][p0 + 64];
    float xs[8] = {xa.x, xa.y, xa.z, xa.w, xc.x, xc.y, xc.z, xc.w};
    float ws[4] = {w4.x, w4.y, w4.z, w4.w};
    #pragma unroll
    for (int ci = 0; ci < 4; ci++)
      #pragma unroll
      for (int pj = 0; pj < 8; pj++) acc[ci][pj] += ws[ci] * xs[pj];
  }
  float4 bias4 = *(const float4*)(biasv + b*64 + c0);
  float bb[4] = {bias4.x, bias4.y, bias4.z, bias4.w};
  #pragma unroll
  for (int ci = 0; ci < 4; ci++) {
    float s1 = 0.f, s2 = 0.f;
    #pragma unroll
    for (int pj = 0; pj < 8; pj++) {
      float z = acc[ci][pj] + bb[ci];
      s1 += z; s2 += z*z;
    }
    #pragma unroll
    for (int off = 1; off < 16; off <<= 1) { s1 += __shfl_xor(s1, off); s2 += __shfl_xor(s2, off); }
    if (pg == 0) { atomicAdd(&lstat[c0+ci], s1); atomicAdd(&lstat[64+c0+ci], s2); }
  }
  __syncthreads();
  if (t < 128) atomicAdd(&statsacc[t], lstat[t]);
}

__global__ __launch_bounds__(256) void k4_out(const float* __restrict__ x,
    const float* __restrict__ Wt, const float* __restrict__ biasv,
    const float* __restrict__ statsacc,
    const float* __restrict__ gamma, const float* __restrict__ beta,
    float* __restrict__ out)
{
  __shared__ float xt[64][128];
  __shared__ float wl[64][64];
  __shared__ float scl[64], shl[64];
  int t = threadIdx.x, blk = blockIdx.x;
  int tile = blk & 31, b = blk >> 5;
  const float* xb = x + ((size_t)b << 18) + tile*128;
  for (int v = t; v < 2048; v += 256) {
    int ch = v >> 5, rem = v & 31;
    *(float4*)&xt[ch][rem*4] = *(const float4*)(xb + ch*4096 + rem*4);
  }
  const float* wb = Wt + ((size_t)b << 12);
  for (int v = t; v < 1024; v += 256)
    *(float4*)&wl[v >> 4][(v & 15)*4] = *(const float4*)(wb + v*4);
  if (t < 64) {
    const float inv_cnt = 1.f / 65536.f;
    float mu  = statsacc[t] * inv_cnt;
    float var = statsacc[64+t] * inv_cnt - mu*mu;
    float sc  = gamma[t] * rsqrtf(var + 1e-5f);
    scl[t] = sc;
    shl[t] = beta[t] - sc*mu;
  }
  __syncthreads();
  int pg = t & 15, cg = t >> 4;
  int p0 = pg*4, c0 = cg*4;
  float acc[4][8];
  #pragma unroll
  for (int ci = 0; ci < 4; ci++)
    #pragma unroll
    for (int pj = 0; pj < 8; pj++) acc[ci][pj] = 0.f;
  #pragma unroll 4
  for (int k = 0; k < 64; k++) {
    float4 w4 = *(const float4*)&wl[k][c0];
    float4 xa = *(const float4*)&xt[k][p0];
    float4 xc = *(const float4*)&xt[k][p0 + 64];
    float xs[8] = {xa.x, xa.y, xa.z, xa.w, xc.x, xc.y, xc.z, xc.w};
    float ws[4] = {w4.x, w4.y, w4.z, w4.w};
    #pragma unroll
    for (int ci = 0; ci < 4; ci++)
      #pragma unroll
      for (int pj = 0; pj < 8; pj++) acc[ci][pj] += ws[ci] * xs[pj];
  }
  float4 bias4 = *(const float4*)(biasv + b*64 + c0);
  float bb[4] = {bias4.x, bias4.y, bias4.z, bias4.w};
  float* ob = out + ((size_t)b << 18) + (size_t)tile*128;
  #pragma unroll
  for (int ci = 0; ci < 4; ci++) {
    int c = c0 + ci;
    float sc = scl[c], sh = shl[c];
    float4 xa = *(const float4*)&xt[c][p0];
    float4 xc = *(const float4*)&xt[c][p0 + 64];
    float4 ra, rb;
    ra.x = sc*(acc[ci][0]+bb[ci]) + sh + xa.x;
    ra.y = sc*(acc[ci][1]+bb[ci]) + sh + xa.y;
    ra.z = sc*(acc[ci][2]+bb[ci]) + sh + xa.z;
    ra.w = sc*(acc[ci][3]+bb[ci]) + sh + xa.w;
    rb.x = sc*(acc[ci][4]+bb[ci]) + sh + xc.x;
    rb.y = sc*(acc[ci][5]+bb[ci]) + sh + xc.y;
    rb.z = sc*(acc[ci][6]+bb[ci]) + sh + xc.z;
    rb.w = sc*(acc[ci][7]+bb[ci]) + sh + xc.w;
    *(float4*)(ob + (size_t)c*4096 + p0)      = ra;
    *(float4*)(ob + (size_t)c*4096 + p0 + 64) = rb;
  }
}

extern "C" void kernel_launch(void* const* d_in, const int* in_sizes, int n_in,
                              void* d_out, int out_size, void* d_ws, size_t ws_size,
                              hipStream_t stream)
{
  const float* x    = (const float*)d_in[0];
  const float* w1   = (const float*)d_in[1];
  const float* b1   = (const float*)d_in[2];
  const float* w21  = (const float*)d_in[3];
  const float* b21  = (const float*)d_in[4];
  const float* w22  = (const float*)d_in[5];
  const float* b22  = (const float*)d_in[6];
  const float* w3   = (const float*)d_in[7];
  const float* b3   = (const float*)d_in[8];
  const float* gamma= (const float*)d_in[9];
  const float* beta = (const float*)d_in[10];

  float* ws       = (float*)d_ws;
  float* kvpart   = ws;              // 512*1024
  float* Wt       = ws + 524288;     // 65536
  float* biasv    = ws + 589824;     // 1024
  float* statsacc = ws + 590848;     // 128
  float* outp     = (float*)d_out;

  // Guarded cooperative attempt: only launch if the runtime's own occupancy
  // model accepts 1 block/CU for this kernel (R8 failed silently on this).
  int dev = 0;
  hipGetDevice(&dev);
  int coop = 0;
  hipDeviceGetAttribute(&coop, hipDeviceAttributeCooperativeLaunch, dev);
  int mab = 0;
  hipError_t oe = hipOccupancyMaxActiveBlocksPerMultiprocessor(
      &mab, (const void*)fused, 1024, 0);
  if (coop && oe == hipSuccess && mab >= 1) {
    void* args[] = {
      (void*)&x, (void*)&w1, (void*)&b1, (void*)&w21, (void*)&b21,
      (void*)&w22, (void*)&b22, (void*)&w3, (void*)&b3,
      (void*)&gamma, (void*)&beta,
      (void*)&kvpart, (void*)&Wt, (void*)&biasv, (void*)&statsacc, (void*)&outp
    };
    hipError_t rc = hipLaunchCooperativeKernel((const void*)fused,
                                               dim3(256), dim3(1024), args, 0, stream);
    if (rc == hipSuccess) return;
  }

  // Fallback: proven 4-kernel path (R9).
  hipLaunchKernelGGL(k1_kv,    dim3(512), dim3(256), 0, stream, x, w1, b1, w22, b22, kvpart, statsacc);
  hipLaunchKernelGGL(k2_wmat,  dim3(16),  dim3(256), 0, stream, kvpart, w3, b3, w21, b21, Wt, biasv);
  hipLaunchKernelGGL(k3_stats, dim3(512), dim3(256), 0, stream, x, Wt, biasv, statsacc);
  hipLaunchKernelGGL(k4_out,   dim3(512), dim3(256), 0, stream, x, Wt, biasv, statsacc, gamma, beta, outp);
}